// Round 8
// baseline (339.662 us; speedup 1.0000x reference)
//
#include <hip/hip_runtime.h>
#include <hip/hip_bf16.h>

// Round 8 = DIAGNOSTIC build (intentionally slowed, still exactly correct).
// R6 structure + a ~50us per-block wall-clock spin between histogram and
// writeback. Purpose: push my dispatch above the ~122us harness poison fills
// so it finally appears in the top-5 counter rows, exposing WRITE_SIZE /
// FETCH_SIZE / VALUBusy for MY kernel (never observed in R1-R7).
// Questions this answers:
//  (1) Is HBM write traffic 1x (201024 KB) or amplified (804096 KB)?
//  (2) Is there RFO fetch traffic (~+206 MB FETCH)?
//  (3) Store-phase BW = WRITE/(dur - spin): 2.8 vs 4.6+ TB/s -> remaining headroom.

#define BATCH 1024
#define SEQ 512
#define VOCAB 50257
#define OUT_COLS (VOCAB - 1)       // 50256
#define HALF_BINS (OUT_COLS / 2)   // 25128 bins per block
#define NWORDS (HALF_BINS / 2)     // 12564 u32 words (2 bins/word)
#define BLOCK 512

__global__ __launch_bounds__(BLOCK) void bow_row_kernel_diag(
    const int* __restrict__ tokens, float* __restrict__ out) {
    __shared__ unsigned int packed[NWORDS];  // 50256 B

    const int half = blockIdx.x;             // 0 or 1
    const int b    = blockIdx.y;             // row
    const int t    = threadIdx.x;
    const int c0   = half * HALF_BINS;

    // Zero LDS.
    const uint4 z = make_uint4(0u, 0u, 0u, 0u);
    for (int i = t; i < NWORDS / 4; i += BLOCK) ((uint4*)packed)[i] = z;
    __syncthreads();

    // Histogram: one token per thread (SEQ == BLOCK).
    {
        int tok = tokens[b * SEQ + t];
        unsigned int bin = (unsigned int)(tok - 1 - c0);  // tok==0 underflows
        if (bin < HALF_BINS)
            atomicAdd(&packed[bin >> 1], (bin & 1) ? 0x10000u : 1u);
    }
    __syncthreads();

    // ---- DIAGNOSTIC SPIN: ~50us per block (s_memrealtime ~100 MHz). ----
    // Identical memory traffic to R6; only adds idle time so the dispatch
    // rises into the rocprof top-5.
    {
        unsigned long long t0 = __builtin_amdgcn_s_memrealtime();
        while (__builtin_amdgcn_s_memrealtime() - t0 < 5000ull) { }
    }

    // Writeback: one uint2 LDS read -> one coalesced float4 store per iter.
    float* orow = out + (size_t)b * OUT_COLS + c0;
    for (int i = t * 4; i < HALF_BINS; i += BLOCK * 4) {
        uint2 w = *(const uint2*)&packed[i >> 1];
        float4 v = make_float4((float)(w.x & 0xffffu), (float)(w.x >> 16),
                               (float)(w.y & 0xffffu), (float)(w.y >> 16));
        *(float4*)(orow + i) = v;
    }
}

extern "C" void kernel_launch(void* const* d_in, const int* in_sizes, int n_in,
                              void* d_out, int out_size, void* d_ws, size_t ws_size,
                              hipStream_t stream) {
    const int* tokens = (const int*)d_in[0];
    float* out = (float*)d_out;

    dim3 grid(2, BATCH);   // (half, row) = 2048 blocks
    bow_row_kernel_diag<<<grid, BLOCK, 0, stream>>>(tokens, out);
}

// Round 9
// 198.098 us; speedup vs baseline: 1.7146x; 1.7146x over previous
//
#include <hip/hip_runtime.h>
#include <hip/hip_bf16.h>

// BagOfWords: input [1024, 512] int32 tokens in [0, 50257).
// Output [1024, 50256] float32: per-row histogram, vocab bin 0 dropped.
//
// R8 diagnostic established: my stores are 1x HBM traffic (WRITE 201278 KB,
// FETCH 2 MB, no RFO); bench dur = ~155us fixed harness poison (d_out ~31 +
// d_ws ~123) + kernel. Kernel was 42.8us = 4.9 TB/s vs 6.7 TB/s demonstrated
// fill BW -> gap is non-overlapped LDS-zero prologue + batch tail.
//
// R9: u16-packed histogram (2 bins/u32 word, counts <= 512 so no overflow,
// atomicAdd(word, 1 or 1<<16)) in 8192-bin chunks: 16 KB LDS, 256 threads
// -> exactly 8 blocks/CU = 32-wave occupancy cap; zeroing work per output
// element HALVED vs R5/R6; 7168 blocks (28/CU, 3.5 batches). Writeback:
// batch 8 ds_read_b64 -> one waitcnt -> 8 coalesced float4 stores (2-way
// LDS bank aliasing on b64 reads is free per m136).

#define BATCH 1024
#define SEQ 512
#define VOCAB 50257
#define OUT_COLS (VOCAB - 1)          // 50256
#define CHUNK 8192                    // bins per block
#define NWORDS (CHUNK / 2)            // 4096 u32 words (16 KB)
#define NBLK_PER_ROW 7                // 6 full + 1104-bin tail
#define BLOCK 256

__global__ __launch_bounds__(BLOCK) void bow_packed_kernel(
    const int* __restrict__ tokens, float* __restrict__ out) {
    __shared__ unsigned int packed[NWORDS];  // 16 KB

    const int c0 = blockIdx.x * CHUNK;
    const int b  = blockIdx.y;
    const int t  = threadIdx.x;

    // Zero LDS: 4096 words = 1024 uint4, 4 per thread.
    const uint4 z = make_uint4(0u, 0u, 0u, 0u);
    #pragma unroll
    for (int k = 0; k < NWORDS / (BLOCK * 4); ++k)
        ((uint4*)packed)[t + k * BLOCK] = z;
    __syncthreads();

    // Histogram: one pass, int2 per thread (512 tokens / 256 threads).
    // tok==0 dropped via unsigned underflow; tail chunk needs no extra
    // check (max tok-1-c0 = 50255-49152 = 1103 < CHUNK).
    {
        const int2 tk = ((const int2*)(tokens + b * SEQ))[t];
        unsigned int bin;
        bin = (unsigned int)(tk.x - 1 - c0);
        if (bin < CHUNK) atomicAdd(&packed[bin >> 1], (bin & 1) ? 0x10000u : 1u);
        bin = (unsigned int)(tk.y - 1 - c0);
        if (bin < CHUNK) atomicAdd(&packed[bin >> 1], (bin & 1) ? 0x10000u : 1u);
    }
    __syncthreads();

    // Writeback: thread t, iter k covers bins [4*(t+k*BLOCK), +4).
    float* orow = out + (size_t)b * OUT_COLS + c0;
    if (c0 + CHUNK <= OUT_COLS) {
        uint2 w[8];
        #pragma unroll
        for (int k = 0; k < 8; ++k)
            w[k] = ((const uint2*)packed)[t + k * BLOCK];
        #pragma unroll
        for (int k = 0; k < 8; ++k) {
            float4 v = make_float4((float)(w[k].x & 0xffffu), (float)(w[k].x >> 16),
                                   (float)(w[k].y & 0xffffu), (float)(w[k].y >> 16));
            *(float4*)(orow + 4 * (t + k * BLOCK)) = v;
        }
    } else {
        const int ncols = OUT_COLS - c0;   // 1104
        for (int i = t * 4; i < ncols; i += BLOCK * 4) {
            uint2 w = ((const uint2*)packed)[i >> 2];
            float4 v = make_float4((float)(w.x & 0xffffu), (float)(w.x >> 16),
                                   (float)(w.y & 0xffffu), (float)(w.y >> 16));
            *(float4*)(orow + i) = v;
        }
    }
}

extern "C" void kernel_launch(void* const* d_in, const int* in_sizes, int n_in,
                              void* d_out, int out_size, void* d_ws, size_t ws_size,
                              hipStream_t stream) {
    const int* tokens = (const int*)d_in[0];
    float* out = (float*)d_out;

    dim3 grid(NBLK_PER_ROW, BATCH);   // (7, 1024) = 7168 blocks
    bow_packed_kernel<<<grid, BLOCK, 0, stream>>>(tokens, out);
}